// Round 1
// baseline (51.151 us; speedup 1.0000x reference)
//
#include <hip/hip_runtime.h>
#include <hip/hip_bf16.h>

// MultiClassCostSensitiveLoss:
//   probs = softmax(y_pred, axis=1)           [N,3]
//   idx   = y_true + 1                        in {0,1,2}
//   se    = (probs[i, idx] - y_true)^2
//   out   = sum( wmap[idx] * se ),  wmap = {2.0, 0.5, 2.0}
//
// Memory-bound: 134 MB read -> floor ~21 us at 6.3 TB/s.

#define BLOCK 256
#define MAX_BLOCKS 2048

__global__ __launch_bounds__(BLOCK) void mccs_loss_kernel(
    const float* __restrict__ y_pred,   // [N,3] row-major
    const int*   __restrict__ y_true,   // [N], values in {-1,0,1}
    float*       __restrict__ out,      // [1], pre-zeroed
    int n)
{
    const int tid    = blockIdx.x * BLOCK + threadIdx.x;
    const int stride = gridDim.x * BLOCK;

    float acc = 0.0f;
    for (int i = tid; i < n; i += stride) {
        // 3 consecutive floats per row: lanes read consecutive 12B chunks -> coalesced.
        const float a = y_pred[3 * i + 0];
        const float b = y_pred[3 * i + 1];
        const float c = y_pred[3 * i + 2];
        const int   t = y_true[i];        // {-1, 0, 1}
        const int idx = t + 1;            // {0, 1, 2}

        // softmax prob of the true class only
        const float m  = fmaxf(a, fmaxf(b, c));
        const float e0 = __expf(a - m);
        const float e1 = __expf(b - m);
        const float e2 = __expf(c - m);
        const float denom = e0 + e1 + e2;
        const float enum_ = (idx == 0) ? e0 : ((idx == 1) ? e1 : e2);
        const float p = enum_ / denom;

        const float d = p - (float)t;
        const float w = (idx == 1) ? 0.5f : 2.0f;   // {2.0, 0.5, 2.0}
        acc = fmaf(w * d, d, acc);
    }

    // wave-64 butterfly-free down-reduce
    #pragma unroll
    for (int off = 32; off > 0; off >>= 1)
        acc += __shfl_down(acc, off, 64);

    __shared__ float s_part[BLOCK / 64];
    const int wave = threadIdx.x >> 6;
    if ((threadIdx.x & 63) == 0) s_part[wave] = acc;
    __syncthreads();

    if (threadIdx.x == 0) {
        float blk = 0.0f;
        #pragma unroll
        for (int w = 0; w < BLOCK / 64; ++w) blk += s_part[w];
        atomicAdd(out, blk);   // device-scope by default on CDNA
    }
}

extern "C" void kernel_launch(void* const* d_in, const int* in_sizes, int n_in,
                              void* d_out, int out_size, void* d_ws, size_t ws_size,
                              hipStream_t stream)
{
    const float* y_pred = (const float*)d_in[0];
    const int*   y_true = (const int*)d_in[1];
    float*       out    = (float*)d_out;

    const int n = in_sizes[1];   // N samples (in_sizes[0] == 3*N)

    // d_out is poisoned (0xAA) once before timing and never re-poisoned:
    // zero it ourselves every launch (graph-capture-safe async memset).
    hipMemsetAsync(out, 0, sizeof(float), stream);

    int blocks = (n + BLOCK - 1) / BLOCK;
    if (blocks > MAX_BLOCKS) blocks = MAX_BLOCKS;
    mccs_loss_kernel<<<blocks, BLOCK, 0, stream>>>(y_pred, y_true, out, n);
}

// Round 2
// 45.648 us; speedup vs baseline: 1.1205x; 1.1205x over previous
//
#include <hip/hip_runtime.h>
#include <hip/hip_bf16.h>

// MultiClassCostSensitiveLoss:
//   probs = softmax(y_pred, axis=1)           [N,3]
//   idx   = y_true + 1                        in {0,1,2}
//   se    = (probs[i, idx] - y_true)^2
//   out   = sum( wmap[idx] * se ),  wmap = {2.0, 0.5, 2.0}
//
// Memory-bound: 134 MB read. R1: 4 rows/thread -> 3x float4 + 1x int4 loads
// (16B/lane coalesced), rcp instead of div. Floor ~21 us at 6.3 TB/s.

#define BLOCK 256
#define MAX_BLOCKS 2048

__device__ __forceinline__ float row_loss(float a, float b, float c, int t) {
    const int idx = t + 1;                    // {0,1,2}
    const float m  = fmaxf(a, fmaxf(b, c));
    const float e0 = __expf(a - m);
    const float e1 = __expf(b - m);
    const float e2 = __expf(c - m);
    const float r  = __builtin_amdgcn_rcpf(e0 + e1 + e2);  // ~1e-5 rel err, fine
    const float en = (idx == 0) ? e0 : ((idx == 1) ? e1 : e2);
    const float p  = en * r;
    const float d  = p - (float)t;
    const float w  = (idx == 1) ? 0.5f : 2.0f;             // {2.0, 0.5, 2.0}
    return w * d * d;
}

__global__ __launch_bounds__(BLOCK) void mccs_loss_kernel(
    const float* __restrict__ y_pred,   // [N,3] row-major
    const int*   __restrict__ y_true,   // [N], values in {-1,0,1}
    float*       __restrict__ out,      // [1], pre-zeroed
    int n)
{
    const int tid    = blockIdx.x * BLOCK + threadIdx.x;
    const int stride = gridDim.x * BLOCK;

    const float4* __restrict__ p4 = (const float4*)y_pred;
    const int4*   __restrict__ t4 = (const int4*)y_true;

    const int n4 = n >> 2;      // groups of 4 rows
    float acc = 0.0f;

    for (int i = tid; i < n4; i += stride) {
        // rows 4i..4i+3 occupy float4 indices 3i..3i+2 (12 floats)
        const float4 v0 = p4[3 * i + 0];   // r0.a r0.b r0.c r1.a
        const float4 v1 = p4[3 * i + 1];   // r1.b r1.c r2.a r2.b
        const float4 v2 = p4[3 * i + 2];   // r2.c r3.a r3.b r3.c
        const int4   tt = t4[i];

        acc += row_loss(v0.x, v0.y, v0.z, tt.x);
        acc += row_loss(v0.w, v1.x, v1.y, tt.y);
        acc += row_loss(v1.z, v1.w, v2.x, tt.z);
        acc += row_loss(v2.y, v2.z, v2.w, tt.w);
    }

    // tail rows (n % 4): first few threads handle them scalar
    const int tail_base = n4 << 2;
    const int rem = n - tail_base;
    if (tid < rem) {
        const int r = tail_base + tid;
        acc += row_loss(y_pred[3 * r + 0], y_pred[3 * r + 1], y_pred[3 * r + 2],
                        y_true[r]);
    }

    // wave-64 down-reduce
    #pragma unroll
    for (int off = 32; off > 0; off >>= 1)
        acc += __shfl_down(acc, off, 64);

    __shared__ float s_part[BLOCK / 64];
    const int wave = threadIdx.x >> 6;
    if ((threadIdx.x & 63) == 0) s_part[wave] = acc;
    __syncthreads();

    if (threadIdx.x == 0) {
        float blk = 0.0f;
        #pragma unroll
        for (int w = 0; w < BLOCK / 64; ++w) blk += s_part[w];
        atomicAdd(out, blk);   // device-scope by default on CDNA
    }
}

extern "C" void kernel_launch(void* const* d_in, const int* in_sizes, int n_in,
                              void* d_out, int out_size, void* d_ws, size_t ws_size,
                              hipStream_t stream)
{
    const float* y_pred = (const float*)d_in[0];
    const int*   y_true = (const int*)d_in[1];
    float*       out    = (float*)d_out;

    const int n = in_sizes[1];   // N samples (in_sizes[0] == 3*N)

    // d_out is poisoned (0xAA) once before timing and never re-poisoned:
    // zero it ourselves every launch (graph-capture-safe async memset).
    hipMemsetAsync(out, 0, sizeof(float), stream);

    const int n4 = n >> 2;
    int blocks = (n4 + BLOCK - 1) / BLOCK;
    if (blocks > MAX_BLOCKS) blocks = MAX_BLOCKS;
    if (blocks < 1) blocks = 1;
    mccs_loss_kernel<<<blocks, BLOCK, 0, stream>>>(y_pred, y_true, out, n);
}

// Round 3
// 45.435 us; speedup vs baseline: 1.1258x; 1.0047x over previous
//
#include <hip/hip_runtime.h>
#include <hip/hip_bf16.h>

// MultiClassCostSensitiveLoss:
//   probs = softmax(y_pred, axis=1)           [N,3]
//   idx   = y_true + 1                        in {0,1,2}
//   se    = (probs[i, idx] - y_true)^2
//   out   = sum( wmap[idx] * se ),  wmap = {2.0, 0.5, 2.0}
//
// Memory-bound: 134 MB read (L3 serves ~half -> ~67 MB HBM).
// R1: 4 rows/thread via float4/int4. R2: manual 4-deep unroll -> 16
// independent 16B loads in flight per thread before any compute.

#define BLOCK 256
#define MAX_BLOCKS 2048

__device__ __forceinline__ float row_loss(float a, float b, float c, int t) {
    const int idx = t + 1;                    // {0,1,2}
    const float m  = fmaxf(a, fmaxf(b, c));
    const float e0 = __expf(a - m);
    const float e1 = __expf(b - m);
    const float e2 = __expf(c - m);
    const float r  = __builtin_amdgcn_rcpf(e0 + e1 + e2);  // ~1e-5 rel err, fine
    const float en = (idx == 0) ? e0 : ((idx == 1) ? e1 : e2);
    const float p  = en * r;
    const float d  = p - (float)t;
    const float w  = (idx == 1) ? 0.5f : 2.0f;             // {2.0, 0.5, 2.0}
    return w * d * d;
}

// loss of 4 consecutive rows packed as 3 float4 + 1 int4
__device__ __forceinline__ float group_loss(float4 v0, float4 v1, float4 v2, int4 tt) {
    float s;
    s  = row_loss(v0.x, v0.y, v0.z, tt.x);
    s += row_loss(v0.w, v1.x, v1.y, tt.y);
    s += row_loss(v1.z, v1.w, v2.x, tt.z);
    s += row_loss(v2.y, v2.z, v2.w, tt.w);
    return s;
}

__global__ __launch_bounds__(BLOCK) void mccs_loss_kernel(
    const float* __restrict__ y_pred,   // [N,3] row-major
    const int*   __restrict__ y_true,   // [N], values in {-1,0,1}
    float*       __restrict__ out,      // [1], pre-zeroed
    int n)
{
    const int tid    = blockIdx.x * BLOCK + threadIdx.x;
    const int stride = gridDim.x * BLOCK;

    const float4* __restrict__ p4 = (const float4*)y_pred;
    const int4*   __restrict__ t4 = (const int4*)y_true;

    const int n4 = n >> 2;      // groups of 4 rows
    float acc = 0.0f;

    int i = tid;
    // main loop: 4 groups per iteration -> 16 independent 16B loads in flight
    for (; i + 3 * stride < n4; i += 4 * stride) {
        const int iA = i, iB = i + stride, iC = i + 2 * stride, iD = i + 3 * stride;

        const float4 a0 = p4[3 * iA + 0], a1 = p4[3 * iA + 1], a2 = p4[3 * iA + 2];
        const float4 b0 = p4[3 * iB + 0], b1 = p4[3 * iB + 1], b2 = p4[3 * iB + 2];
        const float4 c0 = p4[3 * iC + 0], c1 = p4[3 * iC + 1], c2 = p4[3 * iC + 2];
        const float4 d0 = p4[3 * iD + 0], d1 = p4[3 * iD + 1], d2 = p4[3 * iD + 2];
        const int4   ta = t4[iA], tb = t4[iB], tc = t4[iC], td = t4[iD];

        acc += group_loss(a0, a1, a2, ta);
        acc += group_loss(b0, b1, b2, tb);
        acc += group_loss(c0, c1, c2, tc);
        acc += group_loss(d0, d1, d2, td);
    }
    // leftover groups
    for (; i < n4; i += stride) {
        acc += group_loss(p4[3 * i + 0], p4[3 * i + 1], p4[3 * i + 2], t4[i]);
    }

    // tail rows (n % 4): first few threads handle them scalar
    const int tail_base = n4 << 2;
    const int rem = n - tail_base;
    if (tid < rem) {
        const int r = tail_base + tid;
        acc += row_loss(y_pred[3 * r + 0], y_pred[3 * r + 1], y_pred[3 * r + 2],
                        y_true[r]);
    }

    // wave-64 down-reduce
    #pragma unroll
    for (int off = 32; off > 0; off >>= 1)
        acc += __shfl_down(acc, off, 64);

    __shared__ float s_part[BLOCK / 64];
    const int wave = threadIdx.x >> 6;
    if ((threadIdx.x & 63) == 0) s_part[wave] = acc;
    __syncthreads();

    if (threadIdx.x == 0) {
        float blk = 0.0f;
        #pragma unroll
        for (int w = 0; w < BLOCK / 64; ++w) blk += s_part[w];
        atomicAdd(out, blk);   // device-scope by default on CDNA
    }
}

extern "C" void kernel_launch(void* const* d_in, const int* in_sizes, int n_in,
                              void* d_out, int out_size, void* d_ws, size_t ws_size,
                              hipStream_t stream)
{
    const float* y_pred = (const float*)d_in[0];
    const int*   y_true = (const int*)d_in[1];
    float*       out    = (float*)d_out;

    const int n = in_sizes[1];   // N samples (in_sizes[0] == 3*N)

    // d_out is poisoned (0xAA) once before timing and never re-poisoned:
    // zero it ourselves every launch (graph-capture-safe async memset).
    hipMemsetAsync(out, 0, sizeof(float), stream);

    const int n4 = n >> 2;
    int blocks = (n4 + BLOCK - 1) / BLOCK;
    if (blocks > MAX_BLOCKS) blocks = MAX_BLOCKS;
    if (blocks < 1) blocks = 1;
    mccs_loss_kernel<<<blocks, BLOCK, 0, stream>>>(y_pred, y_true, out, n);
}

// Round 4
// 36.187 us; speedup vs baseline: 1.4135x; 1.2556x over previous
//
#include <hip/hip_runtime.h>
#include <hip/hip_bf16.h>

// MultiClassCostSensitiveLoss:
//   probs = softmax(y_pred, axis=1)           [N,3]
//   idx   = y_true + 1                        in {0,1,2}
//   se    = (probs[i, idx] - y_true)^2
//   out   = sum( wmap[idx] * se ),  wmap = {2.0, 0.5, 2.0}
//
// R3 restructure:
//  - global_load_lds (width=16) stages each 1024-row chunk HBM->LDS with
//    perfectly coalesced 16B/lane transfers and NO data VGPRs (regalloc
//    cannot serialize the loads -> real memory-level parallelism).
//  - compute reads rows from LDS (ds_read_b64 x6 + b128 label read).
//  - two-kernel finish: per-block partial -> d_ws, then a 1-wave reduce
//    writes d_out. No memset dispatch, no 2048-way atomic burst.

#define BLOCK 256
#define MAX_BLOCKS 2048
#define CHUNK_ROWS 1024
#define PRED_BYTES (CHUNK_ROWS * 12)   // 12288
#define LBL_BYTES  (CHUNK_ROWS * 4)    // 4096

typedef __attribute__((address_space(3))) void       lds_void;
typedef const __attribute__((address_space(1))) void gbl_void;

__device__ __forceinline__ void gload_lds16(const void* g, void* l) {
    // width must be a literal 16 -> global_load_lds_dwordx4
    __builtin_amdgcn_global_load_lds((gbl_void*)g, (lds_void*)l, 16, 0, 0);
}

__device__ __forceinline__ float row_loss(float a, float b, float c, int t) {
    const int idx = t + 1;                    // {0,1,2}
    const float m  = fmaxf(a, fmaxf(b, c));
    const float e0 = __expf(a - m);
    const float e1 = __expf(b - m);
    const float e2 = __expf(c - m);
    const float r  = __builtin_amdgcn_rcpf(e0 + e1 + e2);  // ~1e-5 rel err, fine
    const float en = (idx == 0) ? e0 : ((idx == 1) ? e1 : e2);
    const float p  = en * r;
    const float d  = p - (float)t;
    const float w  = (idx == 1) ? 0.5f : 2.0f;             // {2.0, 0.5, 2.0}
    return w * d * d;
}

__global__ __launch_bounds__(BLOCK) void mccs_partials(
    const float* __restrict__ y_pred,   // [N,3] row-major
    const int*   __restrict__ y_true,   // [N], values in {-1,0,1}
    float*       __restrict__ partials, // [gridDim.x]
    int n)
{
    __shared__ __align__(16) char lds[PRED_BYTES + LBL_BYTES];  // 16 KB
    const int t    = threadIdx.x;
    const int wave = t >> 6;
    const int lane = t & 63;

    const int nchunks = n / CHUNK_ROWS;
    float acc = 0.0f;

    for (int c = blockIdx.x; c < nchunks; c += gridDim.x) {
        const long r0 = (long)c * CHUNK_ROWS;
        const char* gp = (const char*)y_pred + r0 * 12;  // 12288 B of preds
        const char* gl = (const char*)y_true + r0 * 4;   //  4096 B of labels

        // stage preds: 12 wave-level 1KB DMA transfers (3 per wave)
        #pragma unroll
        for (int j = 0; j < 3; ++j) {
            const int seg = (wave * 3 + j) * 1024;       // 1 KB per wave-instr
            gload_lds16(gp + seg + lane * 16, (char*)lds + seg);
        }
        // stage labels: 4 wave-level 1KB transfers (1 per wave)
        {
            const int seg = wave * 1024;
            gload_lds16(gl + seg + lane * 16, (char*)lds + PRED_BYTES + seg);
        }
        __syncthreads();   // compiler drains vmcnt before s_barrier

        // thread t owns rows 4t..4t+3: floats [12t, 12t+12) = 6 x float2
        const float2* f2 = (const float2*)(lds + 48 * t);
        const float2 u0 = f2[0], u1 = f2[1], u2 = f2[2];
        const float2 u3 = f2[3], u4 = f2[4], u5 = f2[5];
        const int4 tt = *(const int4*)(lds + PRED_BYTES + 16 * t);

        acc += row_loss(u0.x, u0.y, u1.x, tt.x);
        acc += row_loss(u1.y, u2.x, u2.y, tt.y);
        acc += row_loss(u3.x, u3.y, u4.x, tt.z);
        acc += row_loss(u4.y, u5.x, u5.y, tt.w);

        __syncthreads();   // protect LDS before next chunk's DMA overwrites
    }

    // tail rows (n % CHUNK_ROWS): direct global loads, grid-strided
    {
        const long tail = (long)nchunks * CHUNK_ROWS;
        for (long r = tail + (long)blockIdx.x * BLOCK + t; r < n;
             r += (long)gridDim.x * BLOCK) {
            acc += row_loss(y_pred[3 * r + 0], y_pred[3 * r + 1],
                            y_pred[3 * r + 2], y_true[r]);
        }
    }

    // wave-64 down-reduce, then LDS reduce of 4 wave partials
    #pragma unroll
    for (int off = 32; off > 0; off >>= 1)
        acc += __shfl_down(acc, off, 64);

    __shared__ float s_part[BLOCK / 64];
    if (lane == 0) s_part[wave] = acc;
    __syncthreads();

    if (t == 0) {
        float blk = 0.0f;
        #pragma unroll
        for (int w = 0; w < BLOCK / 64; ++w) blk += s_part[w];
        partials[blockIdx.x] = blk;    // plain store, no atomic
    }
}

__global__ __launch_bounds__(64) void mccs_final(
    const float* __restrict__ partials, int nparts, float* __restrict__ out)
{
    float s = 0.0f;
    for (int i = threadIdx.x; i < nparts; i += 64) s += partials[i];
    #pragma unroll
    for (int off = 32; off > 0; off >>= 1)
        s += __shfl_down(s, off, 64);
    if (threadIdx.x == 0) *out = s;    // overwrite: no memset needed
}

extern "C" void kernel_launch(void* const* d_in, const int* in_sizes, int n_in,
                              void* d_out, int out_size, void* d_ws, size_t ws_size,
                              hipStream_t stream)
{
    const float* y_pred = (const float*)d_in[0];
    const int*   y_true = (const int*)d_in[1];
    float*       out    = (float*)d_out;
    float*       parts  = (float*)d_ws;       // >= MAX_BLOCKS*4 bytes

    const int n = in_sizes[1];   // N samples (in_sizes[0] == 3*N)

    int nchunks = n / CHUNK_ROWS;
    int blocks = nchunks < MAX_BLOCKS ? nchunks : MAX_BLOCKS;
    if (blocks < 1) blocks = 1;

    mccs_partials<<<blocks, BLOCK, 0, stream>>>(y_pred, y_true, parts, n);
    mccs_final<<<1, 64, 0, stream>>>(parts, blocks, out);
}

// Round 5
// 28.612 us; speedup vs baseline: 1.7877x; 1.2647x over previous
//
#include <hip/hip_runtime.h>
#include <hip/hip_bf16.h>

// MultiClassCostSensitiveLoss:
//   probs = softmax(y_pred, axis=1)           [N,3]
//   idx   = y_true + 1                        in {0,1,2}
//   se    = (probs[i, idx] - y_true)^2
//   out   = sum( wmap[idx] * se ),  wmap = {2.0, 0.5, 2.0}
//
// R4: one 1024-row chunk per block (8192 blocks) -> HW block-retirement
// pipelining replaces the lock-stepped in-block chunk loop. Preds staged
// HBM->LDS via global_load_lds width=16 (no data VGPRs, fully coalesced);
// labels loaded directly as per-thread int4 (16B-aligned, lane-contiguous).
// Final reduce fattened to 1024 threads.

#define BLOCK 256
#define CHUNK_ROWS 1024
#define PRED_BYTES (CHUNK_ROWS * 12)   // 12288 B of preds per chunk

typedef __attribute__((address_space(3))) void       lds_void;
typedef const __attribute__((address_space(1))) void gbl_void;

__device__ __forceinline__ void gload_lds16(const void* g, void* l) {
    // width must be a literal 16 -> global_load_lds_dwordx4
    __builtin_amdgcn_global_load_lds((gbl_void*)g, (lds_void*)l, 16, 0, 0);
}

__device__ __forceinline__ float row_loss(float a, float b, float c, int t) {
    const int idx = t + 1;                    // {0,1,2}
    const float m  = fmaxf(a, fmaxf(b, c));
    const float e0 = __expf(a - m);
    const float e1 = __expf(b - m);
    const float e2 = __expf(c - m);
    const float r  = __builtin_amdgcn_rcpf(e0 + e1 + e2);  // ~1e-5 rel err, fine
    const float en = (idx == 0) ? e0 : ((idx == 1) ? e1 : e2);
    const float p  = en * r;
    const float d  = p - (float)t;
    const float w  = (idx == 1) ? 0.5f : 2.0f;             // {2.0, 0.5, 2.0}
    return w * d * d;
}

__global__ __launch_bounds__(BLOCK) void mccs_partials(
    const float* __restrict__ y_pred,   // [N,3] row-major
    const int*   __restrict__ y_true,   // [N], values in {-1,0,1}
    float*       __restrict__ partials, // [gridDim.x]
    int n)
{
    __shared__ __align__(16) char lds[PRED_BYTES];  // 12 KB
    const int t    = threadIdx.x;
    const int wave = t >> 6;
    const int lane = t & 63;

    const int nchunks = n / CHUNK_ROWS;
    float acc = 0.0f;

    // normally gridDim.x == nchunks -> exactly one iteration per block
    for (int c = blockIdx.x; c < nchunks; c += gridDim.x) {
        const long r0 = (long)c * CHUNK_ROWS;
        const char* gp = (const char*)y_pred + r0 * 12;  // 12288 B of preds

        // stage preds: 12 wave-level 1KB DMA transfers (3 per wave)
        #pragma unroll
        for (int j = 0; j < 3; ++j) {
            const int seg = (wave * 3 + j) * 1024;       // 1 KB per wave-instr
            gload_lds16(gp + seg + lane * 16, (char*)lds + seg);
        }

        // labels for rows 4t..4t+3: 16B-aligned, lane-contiguous int4
        const int4 tt = *(const int4*)(y_true + r0 + 4 * t);

        __syncthreads();   // drains vmcnt -> preds resident in LDS

        // thread t owns rows 4t..4t+3: floats [12t, 12t+12) = 6 x float2
        const float2* f2 = (const float2*)(lds + 48 * t);
        const float2 u0 = f2[0], u1 = f2[1], u2 = f2[2];
        const float2 u3 = f2[3], u4 = f2[4], u5 = f2[5];

        acc += row_loss(u0.x, u0.y, u1.x, tt.x);
        acc += row_loss(u1.y, u2.x, u2.y, tt.y);
        acc += row_loss(u3.x, u3.y, u4.x, tt.z);
        acc += row_loss(u4.y, u5.x, u5.y, tt.w);

        __syncthreads();   // protect LDS if this block loops again
    }

    // tail rows (n % CHUNK_ROWS): direct global loads, grid-strided
    {
        const long tail = (long)nchunks * CHUNK_ROWS;
        for (long r = tail + (long)blockIdx.x * BLOCK + t; r < n;
             r += (long)gridDim.x * BLOCK) {
            acc += row_loss(y_pred[3 * r + 0], y_pred[3 * r + 1],
                            y_pred[3 * r + 2], y_true[r]);
        }
    }

    // wave-64 down-reduce, then LDS reduce of 4 wave partials
    #pragma unroll
    for (int off = 32; off > 0; off >>= 1)
        acc += __shfl_down(acc, off, 64);

    __shared__ float s_part[BLOCK / 64];
    if (lane == 0) s_part[wave] = acc;
    __syncthreads();

    if (t == 0) {
        float blk = 0.0f;
        #pragma unroll
        for (int w = 0; w < BLOCK / 64; ++w) blk += s_part[w];
        partials[blockIdx.x] = blk;    // plain store, no atomic
    }
}

#define FBLOCK 1024
__global__ __launch_bounds__(FBLOCK) void mccs_final(
    const float* __restrict__ partials, int nparts, float* __restrict__ out)
{
    float s = 0.0f;
    for (int i = threadIdx.x; i < nparts; i += FBLOCK) s += partials[i];
    #pragma unroll
    for (int off = 32; off > 0; off >>= 1)
        s += __shfl_down(s, off, 64);

    __shared__ float s_part[FBLOCK / 64];
    const int wave = threadIdx.x >> 6;
    if ((threadIdx.x & 63) == 0) s_part[wave] = s;
    __syncthreads();
    if (threadIdx.x == 0) {
        float tot = 0.0f;
        #pragma unroll
        for (int w = 0; w < FBLOCK / 64; ++w) tot += s_part[w];
        *out = tot;    // overwrite: no memset needed
    }
}

extern "C" void kernel_launch(void* const* d_in, const int* in_sizes, int n_in,
                              void* d_out, int out_size, void* d_ws, size_t ws_size,
                              hipStream_t stream)
{
    const float* y_pred = (const float*)d_in[0];
    const int*   y_true = (const int*)d_in[1];
    float*       out    = (float*)d_out;
    float*       parts  = (float*)d_ws;

    const int n = in_sizes[1];   // N samples (in_sizes[0] == 3*N)

    int nchunks = n / CHUNK_ROWS;               // 8192 at N=8.39M
    int blocks = nchunks < 1 ? 1 : nchunks;
    const int ws_cap = (int)(ws_size / sizeof(float));
    if (blocks > ws_cap) blocks = ws_cap;       // safety vs workspace size
    if (blocks > 8192) blocks = 8192;

    mccs_partials<<<blocks, BLOCK, 0, stream>>>(y_pred, y_true, parts, n);
    mccs_final<<<1, FBLOCK, 0, stream>>>(parts, blocks, out);
}